// Round 3
// baseline (245.955 us; speedup 1.0000x reference)
//
#include <hip/hip_runtime.h>
#include <hip/hip_bf16.h>

#define NJ 7
#define DTC 0.1f
#define ACTION_RANGE 50.0f
#define MAX_VEL 20.0f
#define PI_F 3.14159265358979323846f
#define TWO_PI_F 6.28318530717958647692f
#define INV_TWO_PI_F 0.15915494309189533577f

__device__ __forceinline__ float bf2f(__hip_bfloat16 x){ return __bfloat162float(x); }

// dtype-dispatched load/store: isb==true -> buffer is bf16, else fp32.
// isb is wave-uniform so this is a scalar branch, not divergence.
__device__ __forceinline__ float ldv(const void* p, int i, bool isb){
  return isb ? __bfloat162float(((const __hip_bfloat16*)p)[i]) : ((const float*)p)[i];
}
__device__ __forceinline__ void stv(void* p, int i, float v, bool isb){
  if (isb) ((__hip_bfloat16*)p)[i] = __float2bfloat16(v);
  else     ((float*)p)[i] = v;
}

// exp of se(3) twist xi = Aj * s ; outputs rotation R (row-major 3x3) and translation P
__device__ __forceinline__ void exp_se3_Rp(const float* Aj, float s, float* R, float* P){
  float wx=Aj[0]*s, wy=Aj[1]*s, wz=Aj[2]*s;
  float vx=Aj[3]*s, vy=Aj[4]*s, vz=Aj[5]*s;
  float th2 = wx*wx+wy*wy+wz*wz;
  float th = sqrtf(th2);
  float a,b,c;
  if (th < 0.25f){
    float th4 = th2*th2;
    a = 1.f - th2*(1.f/6.f) + th4*(1.f/120.f);
    b = 0.5f - th2*(1.f/24.f) + th4*(1.f/720.f);
    c = (1.f/6.f) - th2*(1.f/120.f) + th4*(1.f/5040.f);
  } else {
    float sn = sinf(th);
    float cs = cosf(th);
    float inv = 1.f/th;
    float inv2 = inv*inv;
    a = sn*inv;
    b = (1.f-cs)*inv2;
    c = (th-sn)*inv2*inv;
  }
  R[0]=1.f+b*(wx*wx-th2); R[1]=b*wx*wy-a*wz;      R[2]=b*wx*wz+a*wy;
  R[3]=b*wx*wy+a*wz;      R[4]=1.f+b*(wy*wy-th2); R[5]=b*wy*wz-a*wx;
  R[6]=b*wx*wz-a*wy;      R[7]=b*wy*wz+a*wx;      R[8]=1.f+b*(wz*wz-th2);
  float V0=1.f+c*(wx*wx-th2), V1=c*wx*wy-b*wz,      V2=c*wx*wz+b*wy;
  float V3=c*wx*wy+b*wz,      V4=1.f+c*(wy*wy-th2), V5=c*wy*wz-b*wx;
  float V6=c*wx*wz-b*wy,      V7=c*wy*wz+b*wx,      V8=1.f+c*(wz*wz-th2);
  P[0]=V0*vx+V1*vy+V2*vz;
  P[1]=V3*vx+V4*vy+V5*vz;
  P[2]=V6*vx+V7*vy+V8*vz;
}

__device__ __forceinline__ void mul33(const float* X, const float* Y, float* Z){
  #pragma unroll
  for (int r=0;r<3;r++){
    float x0=X[r*3+0], x1=X[r*3+1], x2=X[r*3+2];
    Z[r*3+0]=x0*Y[0]+x1*Y[3]+x2*Y[6];
    Z[r*3+1]=x0*Y[1]+x1*Y[4]+x2*Y[7];
    Z[r*3+2]=x0*Y[2]+x1*Y[5]+x2*Y[8];
  }
}

// V' = Ad(T) V :  w'=R w ; v' = p x (R w) + R v   (alias-safe)
__device__ __forceinline__ void ad_apply(const float* R, const float* p, const float* Vin, float* Vout){
  float i0=Vin[0],i1=Vin[1],i2=Vin[2],i3=Vin[3],i4=Vin[4],i5=Vin[5];
  float w0 = R[0]*i0+R[1]*i1+R[2]*i2;
  float w1 = R[3]*i0+R[4]*i1+R[5]*i2;
  float w2 = R[6]*i0+R[7]*i1+R[8]*i2;
  float r0 = R[0]*i3+R[1]*i4+R[2]*i5;
  float r1 = R[3]*i3+R[4]*i4+R[5]*i5;
  float r2 = R[6]*i3+R[7]*i4+R[8]*i5;
  float p0=p[0],p1=p[1],p2=p[2];
  Vout[0]=w0; Vout[1]=w1; Vout[2]=w2;
  Vout[3]=p1*w2-p2*w1+r0;
  Vout[4]=p2*w0-p0*w2+r1;
  Vout[5]=p0*w1-p1*w0+r2;
}

// F' = Ad(T)^T F:  m' = R^T (m - p x f) ; f' = R^T f   (alias-safe)
__device__ __forceinline__ void adT_apply(const float* R, const float* p, const float* Fin, float* Fout){
  float m0=Fin[0],m1=Fin[1],m2=Fin[2],f0=Fin[3],f1=Fin[4],f2=Fin[5];
  float p0=p[0],p1=p[1],p2=p[2];
  float cx = m0 - (p1*f2 - p2*f1);
  float cy = m1 - (p2*f0 - p0*f2);
  float cz = m2 - (p0*f1 - p1*f0);
  float o0 = R[0]*cx + R[3]*cy + R[6]*cz;
  float o1 = R[1]*cx + R[4]*cy + R[7]*cz;
  float o2 = R[2]*cx + R[5]*cy + R[8]*cz;
  float o3 = R[0]*f0 + R[3]*f1 + R[6]*f2;
  float o4 = R[1]*f0 + R[4]*f1 + R[7]*f2;
  float o5 = R[2]*f0 + R[5]*f1 + R[8]*f2;
  Fout[0]=o0;Fout[1]=o1;Fout[2]=o2;Fout[3]=o3;Fout[4]=o4;Fout[5]=o5;
}

__device__ __forceinline__ void gmatvec(const float* G, const float* v, float* out){
  float v0=v[0],v1=v[1],v2=v[2],v3=v[3],v4=v[4],v5=v[5];
  #pragma unroll
  for (int r=0;r<6;r++){
    out[r] = G[r*6+0]*v0+G[r*6+1]*v1+G[r*6+2]*v2+G[r*6+3]*v3+G[r*6+4]*v4+G[r*6+5]*v5;
  }
}

// per-thread LDS strides (odd -> gcd(stride,32)=1 -> conflict-free 2 lanes/bank)
#define RP_STRIDE 85   // 7 joints x (9 R + 3 p) = 84 used
#define MM_STRIDE 57   // 7x7 mass matrix (49) + rhs (7)

__global__ __launch_bounds__(64) void arm_rk4_kernel(
    const void* __restrict__ g_state,
    const void* __restrict__ g_torque,
    const void* __restrict__ g_M,
    const void* __restrict__ g_A,
    const void* __restrict__ g_L,
    const void* __restrict__ g_grav,
    const void* __restrict__ g_ftip,
    void* __restrict__ g_out,
    int B)
{
  __shared__ float sA[42];       // A[7][6]
  __shared__ float sG[252];      // G[7][6][6] = L L^T
  __shared__ float sMinvR[72];   // inv_T(M_i): R^T             i=0..7
  __shared__ float sMinvp[24];   //             -R^T p
  __shared__ float sMR[72];      // M_i: R (for FK)
  __shared__ float sMp[24];      //      p
  __shared__ float sgrav[3];
  __shared__ float sftip[6];
  __shared__ float sRP[64*RP_STRIDE];
  __shared__ float sMm[64*MM_STRIDE];

  // ---- dtype detection from gravity values (wave-uniform) ----
  // bf16 layout: element 1 == -9.8125 ; fp32 layout: bf16-view element 1 is
  // the high half of 0.0f == 0. Decide once, use everywhere.
  const bool isb = fabsf(bf2f(((const __hip_bfloat16*)g_grav)[1]) + 9.8f) < 0.5f;

  const int t = threadIdx.x;
  for (int x=t; x<42; x+=64) sA[x] = ldv(g_A, x, isb);
  for (int x=t; x<252; x+=64){
    int i = x/36; int rc = x - i*36; int r = rc/6; int c = rc - r*6;
    float s = 0.f;
    #pragma unroll
    for (int k=0;k<6;k++) s += ldv(g_L, i*36+r*6+k, isb) * ldv(g_L, i*36+c*6+k, isb);
    sG[x] = s;
  }
  if (t < 8){
    float R[9], p[3];
    #pragma unroll
    for (int r=0;r<3;r++){
      #pragma unroll
      for (int c=0;c<3;c++) R[r*3+c] = ldv(g_M, t*16 + r*4 + c, isb);
      p[r] = ldv(g_M, t*16 + r*4 + 3, isb);
    }
    #pragma unroll
    for (int r=0;r<3;r++){
      #pragma unroll
      for (int c=0;c<3;c++){ sMR[t*9+r*3+c] = R[r*3+c]; sMinvR[t*9+r*3+c] = R[c*3+r]; }
      sMp[t*3+r] = p[r];
      sMinvp[t*3+r] = -(R[0*3+r]*p[0] + R[1*3+r]*p[1] + R[2*3+r]*p[2]);
    }
  }
  if (t == 0){ for (int k=0;k<3;k++) sgrav[k] = ldv(g_grav, k, isb); }
  if (t == 1){ for (int k=0;k<6;k++) sftip[k] = ldv(g_ftip, k, isb); }
  __syncthreads();

  const int b = blockIdx.x * 64 + t;
  if (b >= B) return;

  const int rpB = t*RP_STRIDE;
  const int mmB = t*MM_STRIDE;

  float q0[7], dq0[7], qf[7];
  #pragma unroll
  for (int i=0;i<7;i++){
    q0[i]  = ldv(g_state, b*14+i, isb);
    dq0[i] = ldv(g_state, b*14+7+i, isb);
    qf[i]  = ldv(g_torque, b*7+i, isb) * ACTION_RANGE;
  }

  float kq[7], kdd[7], accq[7], accdq[7];
  #pragma unroll
  for (int i=0;i<7;i++){ kq[i]=0.f; kdd[i]=0.f; accq[i]=0.f; accdq[i]=0.f; }

  #pragma unroll 1
  for (int st=0; st<4; ++st){
    const float cin = (st==0) ? 0.f : ((st==3) ? DTC : 0.5f*DTC);
    const float wgt = (st==0||st==3) ? (DTC/6.f) : (DTC/3.f);
    float qs[7], dqs[7];
    #pragma unroll
    for (int i=0;i<7;i++){ qs[i]=q0[i]+cin*kq[i]; dqs[i]=dq0[i]+cin*kdd[i]; }

    // ---- joint transforms T_i = exp(-A_i q_i) * inv(M_i): store (R,p) in LDS ----
    #pragma unroll
    for (int i=0;i<7;i++){
      float Re[9], Pe[3];
      exp_se3_Rp(&sA[i*6], -qs[i], Re, Pe);
      float* Rt = &sRP[rpB + i*12];
      float* Pt = Rt + 9;
      mul33(Re, &sMinvR[i*9], Rt);
      #pragma unroll
      for (int r=0;r<3;r++)
        Pt[r] = Re[r*3+0]*sMinvp[i*3+0] + Re[r*3+1]*sMinvp[i*3+1] + Re[r*3+2]*sMinvp[i*3+2] + Pe[r];
    }

    // ---- forward pass (bias torque h): V, Vd ----
    float Varr[7][6], Vdarr[7][6];
    float Vc[6]  = {0.f,0.f,0.f,0.f,0.f,0.f};
    float Vdc[6] = {0.f,0.f,0.f,-sgrav[0],-sgrav[1],-sgrav[2]};
    #pragma unroll
    for (int i=0;i<7;i++){
      const float* R = &sRP[rpB+i*12];
      const float* p = R+9;
      float di = dqs[i];
      float t1[6]; ad_apply(R,p,Vc,t1);
      #pragma unroll
      for (int k=0;k<6;k++) Vc[k] = t1[k] + sA[i*6+k]*di;
      float t2[6]; ad_apply(R,p,Vdc,t2);
      float w0=Vc[0],w1=Vc[1],w2=Vc[2],v0=Vc[3],v1=Vc[4],v2=Vc[5];
      float a0=sA[i*6+0],a1=sA[i*6+1],a2=sA[i*6+2],a3=sA[i*6+3],a4=sA[i*6+4],a5=sA[i*6+5];
      Vdc[0]=t2[0]+(w1*a2-w2*a1)*di;
      Vdc[1]=t2[1]+(w2*a0-w0*a2)*di;
      Vdc[2]=t2[2]+(w0*a1-w1*a0)*di;
      Vdc[3]=t2[3]+((v1*a2-v2*a1)+(w1*a5-w2*a4))*di;
      Vdc[4]=t2[4]+((v2*a0-v0*a2)+(w2*a3-w0*a5))*di;
      Vdc[5]=t2[5]+((v0*a1-v1*a0)+(w0*a4-w1*a3))*di;
      #pragma unroll
      for (int k=0;k<6;k++){ Varr[i][k]=Vc[k]; Vdarr[i][k]=Vdc[k]; }
    }

    // ---- backward pass (bias torque h) ----
    float F[6];
    adT_apply(&sMinvR[7*9], &sMinvp[7*3], sftip, F);  // AdT_end^T Ftip
    float htau[7];
    #pragma unroll
    for (int i=6;i>=0;i--){
      if (i<6) adT_apply(&sRP[rpB+(i+1)*12], &sRP[rpB+(i+1)*12+9], F, F);
      const float* Gi = &sG[i*36];
      float gv[6], gvd[6];
      gmatvec(Gi, Varr[i], gv);
      gmatvec(Gi, Vdarr[i], gvd);
      float w0=Varr[i][0],w1=Varr[i][1],w2=Varr[i][2],v0=Varr[i][3],v1=Varr[i][4],v2=Varr[i][5];
      F[0] += gvd[0] + (w1*gv[2]-w2*gv[1]) + (v1*gv[5]-v2*gv[4]);
      F[1] += gvd[1] + (w2*gv[0]-w0*gv[2]) + (v2*gv[3]-v0*gv[5]);
      F[2] += gvd[2] + (w0*gv[1]-w1*gv[0]) + (v0*gv[4]-v1*gv[3]);
      F[3] += gvd[3] + (w1*gv[5]-w2*gv[4]);
      F[4] += gvd[4] + (w2*gv[3]-w0*gv[5]);
      F[5] += gvd[5] + (w0*gv[4]-w1*gv[3]);
      htau[i] = F[0]*sA[i*6+0]+F[1]*sA[i*6+1]+F[2]*sA[i*6+2]+F[3]*sA[i*6+3]+F[4]*sA[i*6+4]+F[5]*sA[i*6+5];
    }

    // ---- mass matrix columns (dq=0, g=0, ftip=0, ddq=e_j); symmetric fill ----
    #pragma unroll 1
    for (int j=0;j<7;j++){
      float cvd[7][6];
      #pragma unroll
      for (int i=0;i<7;i++){
        if (i==j){
          #pragma unroll
          for (int k=0;k<6;k++) cvd[i][k]=sA[i*6+k];
        } else if (i>j){
          ad_apply(&sRP[rpB+i*12], &sRP[rpB+i*12+9], cvd[i-1], cvd[i]);
        }
      }
      float Fc[6] = {0.f,0.f,0.f,0.f,0.f,0.f};
      #pragma unroll
      for (int i=6;i>=0;i--){
        if (i>=j){
          if (i<6) adT_apply(&sRP[rpB+(i+1)*12], &sRP[rpB+(i+1)*12+9], Fc, Fc);
          float gv[6];
          gmatvec(&sG[i*36], cvd[i], gv);
          #pragma unroll
          for (int k=0;k<6;k++) Fc[k] += gv[k];
          float mij = Fc[0]*sA[i*6+0]+Fc[1]*sA[i*6+1]+Fc[2]*sA[i*6+2]+Fc[3]*sA[i*6+3]+Fc[4]*sA[i*6+4]+Fc[5]*sA[i*6+5];
          sMm[mmB + i*7 + j] = mij;
          sMm[mmB + j*7 + i] = mij;
        }
      }
    }

    // ---- LU solve with partial pivoting (mirrors jnp.linalg.solve) ----
    float* Mm  = &sMm[mmB];
    float* rhs = Mm + 49;
    #pragma unroll
    for (int i=0;i<7;i++) rhs[i] = qf[i] - htau[i];

    #pragma unroll 1
    for (int k=0;k<7;k++){
      int pr = k; float pv = fabsf(Mm[k*7+k]);
      for (int r=k+1;r<7;r++){
        float v = fabsf(Mm[r*7+k]);
        if (v > pv){ pv = v; pr = r; }
      }
      if (pr != k){
        for (int c=k;c<7;c++){ float tmp = Mm[k*7+c]; Mm[k*7+c] = Mm[pr*7+c]; Mm[pr*7+c] = tmp; }
        float tmp = rhs[k]; rhs[k] = rhs[pr]; rhs[pr] = tmp;
      }
      float pinv = 1.f / Mm[k*7+k];
      for (int r=k+1;r<7;r++){
        float f = Mm[r*7+k] * pinv;
        for (int c=k+1;c<7;c++) Mm[r*7+c] -= f * Mm[k*7+c];
        rhs[r] -= f * rhs[k];
      }
    }
    float qacc[7];
    #pragma unroll
    for (int i=6;i>=0;i--){
      float s = rhs[i];
      #pragma unroll
      for (int c=i+1;c<7;c++) s -= Mm[i*7+c] * qacc[c];
      qacc[i] = s / Mm[i*7+i];
    }

    // ---- RK4 bookkeeping ----
    #pragma unroll
    for (int i=0;i<7;i++){
      kq[i]  = dqs[i];
      kdd[i] = qacc[i];
      accq[i]  += wgt*kq[i];
      accdq[i] += wgt*kdd[i];
    }
  }

  // ---- wrap / clip ----
  float q1[7], dq1[7];
  #pragma unroll
  for (int i=0;i<7;i++){
    float x = q0[i] + accq[i] + PI_F;
    float m = x - floorf(x * INV_TWO_PI_F) * TWO_PI_F;
    q1[i] = m - PI_F;
    float d = dq0[i] + accdq[i];
    dq1[i] = fminf(fmaxf(d, -MAX_VEL), MAX_VEL);
  }

  // ---- FK: T = prod_i (M_i * exp(A_i q_i)) * M_7 ; output (x, y) ----
  float Rt[9] = {1.f,0.f,0.f, 0.f,1.f,0.f, 0.f,0.f,1.f};
  float Pt[3] = {0.f,0.f,0.f};
  #pragma unroll 1
  for (int i=0;i<7;i++){
    float tmp[9];
    float px = Rt[0]*sMp[i*3+0]+Rt[1]*sMp[i*3+1]+Rt[2]*sMp[i*3+2] + Pt[0];
    float py = Rt[3]*sMp[i*3+0]+Rt[4]*sMp[i*3+1]+Rt[5]*sMp[i*3+2] + Pt[1];
    float pz = Rt[6]*sMp[i*3+0]+Rt[7]*sMp[i*3+1]+Rt[8]*sMp[i*3+2] + Pt[2];
    mul33(Rt, &sMR[i*9], tmp);
    #pragma unroll
    for (int k=0;k<9;k++) Rt[k]=tmp[k];
    Pt[0]=px; Pt[1]=py; Pt[2]=pz;
    float Re[9], Pe[3];
    exp_se3_Rp(&sA[i*6], q1[i], Re, Pe);
    px = Rt[0]*Pe[0]+Rt[1]*Pe[1]+Rt[2]*Pe[2] + Pt[0];
    py = Rt[3]*Pe[0]+Rt[4]*Pe[1]+Rt[5]*Pe[2] + Pt[1];
    pz = Rt[6]*Pe[0]+Rt[7]*Pe[1]+Rt[8]*Pe[2] + Pt[2];
    mul33(Rt, Re, tmp);
    #pragma unroll
    for (int k=0;k<9;k++) Rt[k]=tmp[k];
    Pt[0]=px; Pt[1]=py; Pt[2]=pz;
  }
  float ex = Rt[0]*sMp[7*3+0]+Rt[1]*sMp[7*3+1]+Rt[2]*sMp[7*3+2] + Pt[0];
  float ey = Rt[3]*sMp[7*3+0]+Rt[4]*sMp[7*3+1]+Rt[5]*sMp[7*3+2] + Pt[1];

  // ---- stores ----
  #pragma unroll
  for (int i=0;i<7;i++){
    stv(g_out, b*14+i,   q1[i],  isb);
    stv(g_out, b*14+7+i, dq1[i], isb);
  }
  stv(g_out, B*14 + b*2 + 0, ex, isb);
  stv(g_out, B*14 + b*2 + 1, ey, isb);
}

extern "C" void kernel_launch(void* const* d_in, const int* in_sizes, int n_in,
                              void* d_out, int out_size, void* d_ws, size_t ws_size,
                              hipStream_t stream) {
  const int B = in_sizes[0] / 14;
  const int blocks = (B + 63) / 64;
  arm_rk4_kernel<<<blocks, 64, 0, stream>>>(d_in[0], d_in[1], d_in[2], d_in[3],
                                            d_in[4], d_in[5], d_in[6], d_out, B);
}

// Round 4
// 95.275 us; speedup vs baseline: 2.5815x; 2.5815x over previous
//
#include <hip/hip_runtime.h>
#include <hip/hip_bf16.h>

#define DTC 0.1f
#define ACTION_RANGE 50.0f
#define MAX_VEL 20.0f
#define PI_F 3.14159265358979323846f
#define TWO_PI_F 6.28318530717958647692f
#define INV_TWO_PI_F 0.15915494309189533577f

__device__ __forceinline__ float bf2f(__hip_bfloat16 x){ return __bfloat162float(x); }

// dtype-dispatched load/store (round-3 verified: inputs are bf16, but keep robust)
__device__ __forceinline__ float ldv(const void* p, int i, bool isb){
  return isb ? __bfloat162float(((const __hip_bfloat16*)p)[i]) : ((const float*)p)[i];
}
__device__ __forceinline__ void stv(void* p, int i, float v, bool isb){
  if (isb) ((__hip_bfloat16*)p)[i] = __float2bfloat16(v);
  else     ((float*)p)[i] = v;
}

__device__ __forceinline__ void exp_se3_Rp(const float* Aj, float s, float* R, float* P){
  float wx=Aj[0]*s, wy=Aj[1]*s, wz=Aj[2]*s;
  float vx=Aj[3]*s, vy=Aj[4]*s, vz=Aj[5]*s;
  float th2 = wx*wx+wy*wy+wz*wz;
  float th = sqrtf(th2);
  float a,b,c;
  if (th < 0.25f){
    float th4 = th2*th2;
    a = 1.f - th2*(1.f/6.f) + th4*(1.f/120.f);
    b = 0.5f - th2*(1.f/24.f) + th4*(1.f/720.f);
    c = (1.f/6.f) - th2*(1.f/120.f) + th4*(1.f/5040.f);
  } else {
    float sn = sinf(th), cs = cosf(th);
    float inv = 1.f/th, inv2 = inv*inv;
    a = sn*inv;
    b = (1.f-cs)*inv2;
    c = (th-sn)*inv2*inv;
  }
  R[0]=1.f+b*(wx*wx-th2); R[1]=b*wx*wy-a*wz;      R[2]=b*wx*wz+a*wy;
  R[3]=b*wx*wy+a*wz;      R[4]=1.f+b*(wy*wy-th2); R[5]=b*wy*wz-a*wx;
  R[6]=b*wx*wz-a*wy;      R[7]=b*wy*wz+a*wx;      R[8]=1.f+b*(wz*wz-th2);
  float V0=1.f+c*(wx*wx-th2), V1=c*wx*wy-b*wz,      V2=c*wx*wz+b*wy;
  float V3=c*wx*wy+b*wz,      V4=1.f+c*(wy*wy-th2), V5=c*wy*wz-b*wx;
  float V6=c*wx*wz-b*wy,      V7=c*wy*wz+b*wx,      V8=1.f+c*(wz*wz-th2);
  P[0]=V0*vx+V1*vy+V2*vz;
  P[1]=V3*vx+V4*vy+V5*vz;
  P[2]=V6*vx+V7*vy+V8*vz;
}

__device__ __forceinline__ void mul33(const float* X, const float* Y, float* Z){
  #pragma unroll
  for (int r=0;r<3;r++){
    float x0=X[r*3+0], x1=X[r*3+1], x2=X[r*3+2];
    Z[r*3+0]=x0*Y[0]+x1*Y[3]+x2*Y[6];
    Z[r*3+1]=x0*Y[1]+x1*Y[4]+x2*Y[7];
    Z[r*3+2]=x0*Y[2]+x1*Y[5]+x2*Y[8];
  }
}

// V' = Ad(T) V (alias-safe)
__device__ __forceinline__ void ad_apply(const float* R, const float* p, const float* Vin, float* Vout){
  float i0=Vin[0],i1=Vin[1],i2=Vin[2],i3=Vin[3],i4=Vin[4],i5=Vin[5];
  float w0 = R[0]*i0+R[1]*i1+R[2]*i2;
  float w1 = R[3]*i0+R[4]*i1+R[5]*i2;
  float w2 = R[6]*i0+R[7]*i1+R[8]*i2;
  float r0 = R[0]*i3+R[1]*i4+R[2]*i5;
  float r1 = R[3]*i3+R[4]*i4+R[5]*i5;
  float r2 = R[6]*i3+R[7]*i4+R[8]*i5;
  float p0=p[0],p1=p[1],p2=p[2];
  Vout[0]=w0; Vout[1]=w1; Vout[2]=w2;
  Vout[3]=p1*w2-p2*w1+r0;
  Vout[4]=p2*w0-p0*w2+r1;
  Vout[5]=p0*w1-p1*w0+r2;
}

// F' = Ad(T)^T F (alias-safe)
__device__ __forceinline__ void adT_apply(const float* R, const float* p, const float* Fin, float* Fout){
  float m0=Fin[0],m1=Fin[1],m2=Fin[2],f0=Fin[3],f1=Fin[4],f2=Fin[5];
  float p0=p[0],p1=p[1],p2=p[2];
  float cx = m0 - (p1*f2 - p2*f1);
  float cy = m1 - (p2*f0 - p0*f2);
  float cz = m2 - (p0*f1 - p1*f0);
  float o0 = R[0]*cx + R[3]*cy + R[6]*cz;
  float o1 = R[1]*cx + R[4]*cy + R[7]*cz;
  float o2 = R[2]*cx + R[5]*cy + R[8]*cz;
  float o3 = R[0]*f0 + R[3]*f1 + R[6]*f2;
  float o4 = R[1]*f0 + R[4]*f1 + R[7]*f2;
  float o5 = R[2]*f0 + R[5]*f1 + R[8]*f2;
  Fout[0]=o0;Fout[1]=o1;Fout[2]=o2;Fout[3]=o3;Fout[4]=o4;Fout[5]=o5;
}

__device__ __forceinline__ void gmatvec(const float* G, const float* v, float* out){
  float v0=v[0],v1=v[1],v2=v[2],v3=v[3],v4=v[4],v5=v[5];
  #pragma unroll
  for (int r=0;r<6;r++)
    out[r] = G[r*6+0]*v0+G[r*6+1]*v1+G[r*6+2]*v2+G[r*6+3]*v3+G[r*6+4]*v4+G[r*6+5]*v5;
}

// per-element LDS work stride: odd -> e*97 mod 32 spreads over distinct banks
#define W_STRIDE 97   // holds 7x12 transforms (84) or 8x12 FK slots (96)

__global__ __launch_bounds__(64) void arm_rk4_kernel(
    const void* __restrict__ g_state,
    const void* __restrict__ g_torque,
    const void* __restrict__ g_M,
    const void* __restrict__ g_A,
    const void* __restrict__ g_L,
    const void* __restrict__ g_grav,
    const void* __restrict__ g_ftip,
    void* __restrict__ g_out,
    int B)
{
  __shared__ float sA[42];       // A[7][6]
  __shared__ float sG[252];      // G = L L^T
  __shared__ float sMinvR[72];   // inv(M_i): R^T, i=0..7
  __shared__ float sMinvp[24];   //            -R^T p
  __shared__ float sMR[72];      // M_i rotation (FK)
  __shared__ float sMp[24];      // M_i translation
  __shared__ float sgrav[3];
  __shared__ float sftip[6];
  __shared__ float sW[8*W_STRIDE];

  const bool isb = fabsf(bf2f(((const __hip_bfloat16*)g_grav)[1]) + 9.8f) < 0.5f;

  const int t = threadIdx.x;
  for (int x=t; x<42; x+=64) sA[x] = ldv(g_A, x, isb);
  for (int x=t; x<252; x+=64){
    int i = x/36; int rc = x - i*36; int rr = rc/6; int cc = rc - rr*6;
    float s = 0.f;
    #pragma unroll
    for (int k=0;k<6;k++) s += ldv(g_L, i*36+rr*6+k, isb) * ldv(g_L, i*36+cc*6+k, isb);
    sG[x] = s;
  }
  if (t < 8){
    float R[9], p[3];
    #pragma unroll
    for (int rr=0;rr<3;rr++){
      #pragma unroll
      for (int cc=0;cc<3;cc++) R[rr*3+cc] = ldv(g_M, t*16 + rr*4 + cc, isb);
      p[rr] = ldv(g_M, t*16 + rr*4 + 3, isb);
    }
    #pragma unroll
    for (int rr=0;rr<3;rr++){
      #pragma unroll
      for (int cc=0;cc<3;cc++){ sMR[t*9+rr*3+cc] = R[rr*3+cc]; sMinvR[t*9+rr*3+cc] = R[cc*3+rr]; }
      sMp[t*3+rr] = p[rr];
      sMinvp[t*3+rr] = -(R[0*3+rr]*p[0] + R[1*3+rr]*p[1] + R[2*3+rr]*p[2]);
    }
  }
  if (t == 0){ for (int k=0;k<3;k++) sgrav[k] = ldv(g_grav, k, isb); }
  if (t == 1){ for (int k=0;k<6;k++) sftip[k] = ldv(g_ftip, k, isb); }
  __syncthreads();

  const int e = t >> 3;          // element within block (0..7)
  const int r = t & 7;           // role: 0..6 = mass column r ; 7 = bias torque h
  int b = blockIdx.x * 8 + e;
  if (b >= B) b = B - 1;         // safe clamp (B divisible by 8 in practice)
  const bool is7 = (r == 7);
  float* W = &sW[e*W_STRIDE];

  // replicated per-element state
  float q0[7], dq0[7], qf[7];
  #pragma unroll
  for (int i=0;i<7;i++){
    q0[i]  = ldv(g_state, b*14+i, isb);
    dq0[i] = ldv(g_state, b*14+7+i, isb);
    qf[i]  = ldv(g_torque, b*7+i, isb) * ACTION_RANGE;
  }
  float kq[7], kdd[7], accq[7], accdq[7];
  #pragma unroll
  for (int i=0;i<7;i++){ kq[i]=0.f; kdd[i]=0.f; accq[i]=0.f; accdq[i]=0.f; }

  // role-dependent tip wrench (constant across stages): role7 gets AdT_end^T ftip
  float Fend[6];
  {
    float tf[6]; adT_apply(&sMinvR[63], &sMinvp[21], sftip, tf);
    #pragma unroll
    for (int k=0;k<6;k++) Fend[k] = is7 ? tf[k] : 0.f;
  }

  #pragma unroll 1
  for (int st=0; st<4; ++st){
    const float cin = (st==0) ? 0.f : ((st==3) ? DTC : 0.5f*DTC);
    const float wgt = (st==0||st==3) ? (DTC/6.f) : (DTC/3.f);
    float qs[7], dqs[7];
    #pragma unroll
    for (int i=0;i<7;i++){ qs[i]=q0[i]+cin*kq[i]; dqs[i]=dq0[i]+cin*kdd[i]; }

    // own joint angle (scalar extraction, no runtime register indexing)
    float qsr = 0.f;
    #pragma unroll
    for (int c=0;c<7;c++) qsr = (r==c) ? qs[c] : qsr;

    // ---- transforms: lane r<7 computes T_r = exp(-A_r q_r) inv(M_r) -> LDS ----
    if (r < 7){
      float Re[9], Pe[3], Rt[9];
      exp_se3_Rp(&sA[r*6], -qsr, Re, Pe);
      mul33(Re, &sMinvR[r*9], Rt);
      #pragma unroll
      for (int k=0;k<9;k++) W[r*12+k] = Rt[k];
      #pragma unroll
      for (int rr=0;rr<3;rr++)
        W[r*12+9+rr] = Re[rr*3+0]*sMinvp[r*3+0] + Re[rr*3+1]*sMinvp[r*3+1]
                     + Re[rr*3+2]*sMinvp[r*3+2] + Pe[rr];
    }
    __syncthreads();

    // ---- unified inverse dynamics (all 64 lanes, uniform code) ----
    // role r<7: dq=0, ddq=e_r, g=0, Ftip=0   -> tau = mass-matrix column r
    // role 7 : dq=dqs, ddq=0, g=grav, Ftip   -> tau = bias h
    float Va[7][6], Vda[7][6];
    float V[6] = {0,0,0,0,0,0};
    float Vd[6];
    Vd[0]=0.f; Vd[1]=0.f; Vd[2]=0.f;
    Vd[3] = is7 ? -sgrav[0] : 0.f;
    Vd[4] = is7 ? -sgrav[1] : 0.f;
    Vd[5] = is7 ? -sgrav[2] : 0.f;
    #pragma unroll
    for (int i=0;i<7;i++){
      const float* R = &W[i*12];
      const float* p = R+9;
      float dqi  = is7 ? dqs[i] : 0.f;
      float ddqi = is7 ? 0.f : ((r==i) ? 1.f : 0.f);
      ad_apply(R,p,V,V);
      #pragma unroll
      for (int k=0;k<6;k++) V[k] += sA[i*6+k]*dqi;
      ad_apply(R,p,Vd,Vd);
      {
        float w0=V[0],w1=V[1],w2=V[2],v0=V[3],v1=V[4],v2=V[5];
        float a0=sA[i*6+0],a1=sA[i*6+1],a2=sA[i*6+2],a3=sA[i*6+3],a4=sA[i*6+4],a5=sA[i*6+5];
        Vd[0] += (w1*a2-w2*a1)*dqi + a0*ddqi;
        Vd[1] += (w2*a0-w0*a2)*dqi + a1*ddqi;
        Vd[2] += (w0*a1-w1*a0)*dqi + a2*ddqi;
        Vd[3] += ((v1*a2-v2*a1)+(w1*a5-w2*a4))*dqi + a3*ddqi;
        Vd[4] += ((v2*a0-v0*a2)+(w2*a3-w0*a5))*dqi + a4*ddqi;
        Vd[5] += ((v0*a1-v1*a0)+(w0*a4-w1*a3))*dqi + a5*ddqi;
      }
      #pragma unroll
      for (int k=0;k<6;k++){ Va[i][k]=V[k]; Vda[i][k]=Vd[k]; }
    }

    float m[7];   // lane r<7: row r of symmetric mass matrix ; lane 7: htau
    {
      float F[6];
      #pragma unroll
      for (int k=0;k<6;k++) F[k] = Fend[k];
      #pragma unroll
      for (int i=6;i>=0;i--){
        if (i<6) adT_apply(&W[(i+1)*12], &W[(i+1)*12+9], F, F);
        float gv[6], gvd[6];
        gmatvec(&sG[i*36], Va[i], gv);
        gmatvec(&sG[i*36], Vda[i], gvd);
        float w0=Va[i][0],w1=Va[i][1],w2=Va[i][2],v0=Va[i][3],v1=Va[i][4],v2=Va[i][5];
        F[0] += gvd[0] + (w1*gv[2]-w2*gv[1]) + (v1*gv[5]-v2*gv[4]);
        F[1] += gvd[1] + (w2*gv[0]-w0*gv[2]) + (v2*gv[3]-v0*gv[5]);
        F[2] += gvd[2] + (w0*gv[1]-w1*gv[0]) + (v0*gv[4]-v1*gv[3]);
        F[3] += gvd[3] + (w1*gv[5]-w2*gv[4]);
        F[4] += gvd[4] + (w2*gv[3]-w0*gv[5]);
        F[5] += gvd[5] + (w0*gv[4]-w1*gv[3]);
        m[i] = F[0]*sA[i*6+0]+F[1]*sA[i*6+1]+F[2]*sA[i*6+2]
             + F[3]*sA[i*6+3]+F[4]*sA[i*6+4]+F[5]*sA[i*6+5];
      }
    }

    // ---- row-parallel LU solve within the 8-lane group (no pivot: SPD) ----
    // rhs_r = qf[r] - htau[r]; htau broadcast from lane 7
    float rhs = 0.f;
    #pragma unroll
    for (int c=0;c<7;c++){
      float hc = __shfl(m[c], 7, 8);
      rhs = (r==c) ? (qf[c]-hc) : rhs;
    }
    #pragma unroll
    for (int k=0;k<7;k++){
      float pvk   = __shfl(m[k], k, 8);
      float pvrhs = __shfl(rhs,  k, 8);
      float pinv  = 1.f/pvk;
      float f = (r>k) ? m[k]*pinv : 0.f;
      #pragma unroll
      for (int c=k+1;c<7;c++){
        float pvc = __shfl(m[c], k, 8);
        m[c] -= f*pvc;
      }
      rhs -= f*pvrhs;
    }
    float x[7];
    #pragma unroll
    for (int i=6;i>=0;i--){
      float di = __shfl(m[i], i, 8);
      float si = __shfl(rhs, i, 8);
      float xi = si/di;
      x[i] = xi;
      rhs -= ((r<i) ? m[i] : 0.f) * xi;
    }

    // ---- RK4 bookkeeping (every lane has the full solution) ----
    #pragma unroll
    for (int i=0;i<7;i++){
      kq[i]  = dqs[i];
      kdd[i] = x[i];
      accq[i]  += wgt*dqs[i];
      accdq[i] += wgt*x[i];
    }
    __syncthreads();  // protect W before next stage's transform writes
  }

  // ---- wrap/clip; extract own-joint scalars (no runtime reg indexing) ----
  float q1r=0.f, dq1r=0.f;
  #pragma unroll
  for (int c=0;c<7;c++){
    float xx = q0[c] + accq[c] + PI_F;
    float mm = xx - floorf(xx * INV_TWO_PI_F) * TWO_PI_F;
    float qv = mm - PI_F;
    float dv = dq0[c] + accdq[c];
    dv = fminf(fmaxf(dv, -MAX_VEL), MAX_VEL);
    q1r  = (r==c) ? qv : q1r;
    dq1r = (r==c) ? dv : dq1r;
  }

  // ---- FK tree: X_r = M_r exp(A_r q1_r) (r<7), X_7 = M_7 ; product left-to-right ----
  {
    float XR[9], Xp[3];
    if (r < 7){
      float Re[9], Pe[3];
      exp_se3_Rp(&sA[r*6], q1r, Re, Pe);
      mul33(&sMR[r*9], Re, XR);
      #pragma unroll
      for (int rr=0;rr<3;rr++)
        Xp[rr] = sMR[r*9+rr*3+0]*Pe[0]+sMR[r*9+rr*3+1]*Pe[1]+sMR[r*9+rr*3+2]*Pe[2] + sMp[r*3+rr];
    } else {
      #pragma unroll
      for (int k=0;k<9;k++) XR[k] = sMR[63+k];
      #pragma unroll
      for (int k=0;k<3;k++) Xp[k] = sMp[21+k];
    }
    #pragma unroll
    for (int k=0;k<9;k++) W[r*12+k]   = XR[k];
    #pragma unroll
    for (int k=0;k<3;k++) W[r*12+9+k] = Xp[k];
  }
  __syncthreads();

  #pragma unroll
  for (int w=4; w>=1; w>>=1){
    float Ra[9], pa[3], Rb[9], pb[3];
    if (r < w){
      #pragma unroll
      for (int k=0;k<9;k++){ Ra[k]=W[(2*r)*12+k]; Rb[k]=W[(2*r+1)*12+k]; }
      #pragma unroll
      for (int k=0;k<3;k++){ pa[k]=W[(2*r)*12+9+k]; pb[k]=W[(2*r+1)*12+9+k]; }
    }
    __syncthreads();
    if (r < w){
      float Rc[9];
      mul33(Ra, Rb, Rc);
      #pragma unroll
      for (int k=0;k<9;k++) W[r*12+k] = Rc[k];
      #pragma unroll
      for (int rr=0;rr<3;rr++)
        W[r*12+9+rr] = Ra[rr*3+0]*pb[0]+Ra[rr*3+1]*pb[1]+Ra[rr*3+2]*pb[2] + pa[rr];
    }
    __syncthreads();
  }

  // ---- stores ----
  if (r < 7){
    stv(g_out, b*14+r,   q1r,  isb);
    stv(g_out, b*14+7+r, dq1r, isb);
  } else {
    stv(g_out, B*14 + b*2 + 0, W[9],  isb);
    stv(g_out, B*14 + b*2 + 1, W[10], isb);
  }
}

extern "C" void kernel_launch(void* const* d_in, const int* in_sizes, int n_in,
                              void* d_out, int out_size, void* d_ws, size_t ws_size,
                              hipStream_t stream) {
  const int B = in_sizes[0] / 14;
  const int blocks = (B + 7) / 8;   // 8 elements per 64-thread block
  arm_rk4_kernel<<<blocks, 64, 0, stream>>>(d_in[0], d_in[1], d_in[2], d_in[3],
                                            d_in[4], d_in[5], d_in[6], d_out, B);
}